// Round 1
// baseline (2777.305 us; speedup 1.0000x reference)
//
#include <hip/hip_runtime.h>
#include <hip/hip_bf16.h>
#include <cstddef>

#define B_DIM 8
#define T_SEQ 4096
#define C_DIM 768
#define M_ROWS (B_DIM * T_SEQ)

// ---------------------------------------------------------------------------
// GEMM (NT): O[m,n] = sum_k A[m,k] * W[n,k]
// A: [M,K] row-major, W: [N,K] row-major, O: [M,N] row-major.
// Tile 64x64, BK=16, 256 threads, 4x4 accumulator per thread. f32.
// blockIdx.z selects among 3 weight matrices (shared A => L2 reuse).
// ---------------------------------------------------------------------------
__global__ __launch_bounds__(256, 2) void gemm_nt3(
    const float* __restrict__ A,
    const float* __restrict__ W0, const float* __restrict__ W1,
    const float* __restrict__ W2,
    float* __restrict__ O0, float* __restrict__ O1, float* __restrict__ O2,
    int M, int N, int K, int sigmoid_which)
{
  const int which = blockIdx.z;
  const float* __restrict__ W = (which == 0) ? W0 : (which == 1) ? W1 : W2;
  float* __restrict__ O = (which == 0) ? O0 : (which == 1) ? O1 : O2;

  // +4 pad: rows stay 16B-aligned for float4 LDS reads, stride 68 breaks
  // power-of-2 bank aliasing.
  __shared__ float As[16][68];
  __shared__ float Bs[16][68];

  const int tid = threadIdx.x;
  const int tx = tid & 15;
  const int ty = tid >> 4;
  const int m0 = blockIdx.x * 64;
  const int n0 = blockIdx.y * 64;
  const int lr = tid >> 2;          // 0..63 (row within tile)
  const int lc = (tid & 3) << 2;    // 0,4,8,12 (k within tile, float4)

  const float* aptr = A + (size_t)(m0 + lr) * K + lc;
  const float* bptr = W + (size_t)(n0 + lr) * K + lc;

  float acc[4][4] = {{0.f}};

  for (int k0 = 0; k0 < K; k0 += 16) {
    float4 a4 = *(const float4*)(aptr + k0);
    float4 b4 = *(const float4*)(bptr + k0);
    __syncthreads();
    As[lc + 0][lr] = a4.x; As[lc + 1][lr] = a4.y;
    As[lc + 2][lr] = a4.z; As[lc + 3][lr] = a4.w;
    Bs[lc + 0][lr] = b4.x; Bs[lc + 1][lr] = b4.y;
    Bs[lc + 2][lr] = b4.z; Bs[lc + 3][lr] = b4.w;
    __syncthreads();
#pragma unroll
    for (int kk = 0; kk < 16; ++kk) {
      float4 av = *(const float4*)(&As[kk][ty << 2]);
      float4 bv = *(const float4*)(&Bs[kk][tx << 2]);
      acc[0][0] += av.x * bv.x; acc[0][1] += av.x * bv.y;
      acc[0][2] += av.x * bv.z; acc[0][3] += av.x * bv.w;
      acc[1][0] += av.y * bv.x; acc[1][1] += av.y * bv.y;
      acc[1][2] += av.y * bv.z; acc[1][3] += av.y * bv.w;
      acc[2][0] += av.z * bv.x; acc[2][1] += av.z * bv.y;
      acc[2][2] += av.z * bv.z; acc[2][3] += av.z * bv.w;
      acc[3][0] += av.w * bv.x; acc[3][1] += av.w * bv.y;
      acc[3][2] += av.w * bv.z; acc[3][3] += av.w * bv.w;
    }
  }

  const bool do_sig = (which == sigmoid_which);
#pragma unroll
  for (int i = 0; i < 4; ++i) {
    float4 r;
    r.x = acc[i][0]; r.y = acc[i][1]; r.z = acc[i][2]; r.w = acc[i][3];
    if (do_sig) {
      r.x = 1.f / (1.f + __expf(-r.x));
      r.y = 1.f / (1.f + __expf(-r.y));
      r.z = 1.f / (1.f + __expf(-r.z));
      r.w = 1.f / (1.f + __expf(-r.w));
    }
    *(float4*)(O + (size_t)(m0 + (ty << 2) + i) * N + n0 + (tx << 2)) = r;
  }
}

// ---------------------------------------------------------------------------
// WKV recurrence. One thread per (b, c) channel, sequential over T in
// scan order. Register ping-pong prefetch of k/v chunks (addresses known
// upfront from scan_indices staged in LDS). Output scattered back to
// natural order: Y[b, si[t], c] = y_t  (fuses gather + inverse scatter).
// NOTE: two named chunk buffers (A/B), all indices compile-time after
// unroll -> stays in VGPRs (no scratch).
// ---------------------------------------------------------------------------
#define WCH 16

#define LOAD_CHUNK(rr, kk_, vv_, base)                     \
  _Pragma("unroll")                                        \
  for (int j = 0; j < WCH; ++j) {                          \
    int r_ = si[(base) + j];                               \
    rr[j] = r_;                                            \
    kk_[j] = Kb[(size_t)r_ * C_DIM];                       \
    vv_[j] = Vb[(size_t)r_ * C_DIM];                       \
  }

#define COMPUTE_CHUNK(rr, kk_, vv_)                        \
  _Pragma("unroll")                                        \
  for (int j = 0; j < WCH; ++j) {                          \
    float kt = kk_[j], vt = vv_[j];                        \
    float ww = u + kt;                                     \
    float p = fmaxf(pp, ww);                               \
    float e1 = __expf(pp - p);                             \
    float e2 = __expf(ww - p);                             \
    float y = (e1 * aa + e2 * vt) / (e1 * bb + e2);        \
    Yb[(size_t)rr[j] * C_DIM] = y;                         \
    float ww2 = w + pp;                                    \
    float p2 = fmaxf(ww2, kt);                             \
    float e1b = __expf(ww2 - p2);                          \
    float e2b = __expf(kt - p2);                           \
    aa = e1b * aa + e2b * vt;                              \
    bb = e1b * bb + e2b;                                   \
    pp = p2;                                               \
  }

__global__ __launch_bounds__(256) void wkv_kernel(
    const float* __restrict__ Kin, const float* __restrict__ Vin,
    const int* __restrict__ sidx,
    const float* __restrict__ decay, const float* __restrict__ first,
    float* __restrict__ Y)
{
  __shared__ int si[T_SEQ];
  for (int i = threadIdx.x; i < T_SEQ; i += 256) si[i] = sidx[i];
  __syncthreads();

  const int b = blockIdx.x;                       // 0..7
  const int c = blockIdx.y * 256 + threadIdx.x;   // 0..767

  const float w = decay[c] * (1.0f / (float)T_SEQ);
  const float u = first[c] * (1.0f / (float)T_SEQ);

  const float* Kb = Kin + (size_t)b * T_SEQ * C_DIM + c;
  const float* Vb = Vin + (size_t)b * T_SEQ * C_DIM + c;
  float* Yb = Y + (size_t)b * T_SEQ * C_DIM + c;

  float aa = 0.f, bb = 0.f, pp = -1e38f;

  int   rA[WCH], rB[WCH];
  float kA[WCH], kB[WCH], vA[WCH], vB[WCH];

  LOAD_CHUNK(rA, kA, vA, 0)
  for (int t0 = 0; t0 < T_SEQ; t0 += 2 * WCH) {
    // chunk B prefetch (t0+WCH always < T_SEQ since T % (2*WCH) == 0)
    LOAD_CHUNK(rB, kB, vB, t0 + WCH)
    COMPUTE_CHUNK(rA, kA, vA)
    if (t0 + 2 * WCH < T_SEQ) {
      LOAD_CHUNK(rA, kA, vA, t0 + 2 * WCH)
    }
    COMPUTE_CHUNK(rB, kB, vB)
  }
}

// ---------------------------------------------------------------------------
// Row LayerNorm over C + sigmoid-gate multiply, in place on Y.
// One 256-thread block per row, 3 elements/thread.
// ---------------------------------------------------------------------------
__global__ __launch_bounds__(256) void ln_gate_kernel(
    float* __restrict__ Y, const float* __restrict__ SR,
    const float* __restrict__ g, const float* __restrict__ bta)
{
  const size_t row = blockIdx.x;
  float* x = Y + row * C_DIM;
  const float* sr = SR + row * C_DIM;
  const int tid = threadIdx.x;

  float vals[3];
  float s = 0.f, s2 = 0.f;
#pragma unroll
  for (int j = 0; j < 3; ++j) {
    float v = x[tid + j * 256];
    vals[j] = v;
    s += v; s2 += v * v;
  }
#pragma unroll
  for (int off = 32; off >= 1; off >>= 1) {
    s  += __shfl_xor(s, off, 64);
    s2 += __shfl_xor(s2, off, 64);
  }
  __shared__ float red[8];
  const int wid = tid >> 6;
  if ((tid & 63) == 0) { red[wid] = s; red[wid + 4] = s2; }
  __syncthreads();
  s  = red[0] + red[1] + red[2] + red[3];
  s2 = red[4] + red[5] + red[6] + red[7];

  const float mu = s * (1.f / (float)C_DIM);
  const float var = s2 * (1.f / (float)C_DIM) - mu * mu;
  const float rsig = rsqrtf(var + 1e-5f);

#pragma unroll
  for (int j = 0; j < 3; ++j) {
    const int cc = tid + j * 256;
    float yv = (vals[j] - mu) * rsig * g[cc] + bta[cc];
    x[cc] = yv * sr[cc];
  }
}

// ---------------------------------------------------------------------------
extern "C" void kernel_launch(void* const* d_in, const int* in_sizes, int n_in,
                              void* d_out, int out_size, void* d_ws, size_t ws_size,
                              hipStream_t stream) {
  const float* x     = (const float*)d_in[0];
  const int*   sidx  = (const int*)  d_in[1];
  const float* decay = (const float*)d_in[2];
  const float* first = (const float*)d_in[3];
  const float* Wk    = (const float*)d_in[4];
  const float* Wv    = (const float*)d_in[5];
  const float* Wr    = (const float*)d_in[6];
  const float* Wo    = (const float*)d_in[7];
  const float* ln_g  = (const float*)d_in[8];
  const float* ln_b  = (const float*)d_in[9];
  float* out = (float*)d_out;

  const size_t N = (size_t)M_ROWS * C_DIM;
  float* Kbuf  = (float*)d_ws;
  float* Vbuf  = Kbuf + N;
  float* SRbuf = Vbuf + N;
  float* Ybuf  = SRbuf + N;

  // 1) k, v, sr = sigmoid(r)
  dim3 g3(M_ROWS / 64, C_DIM / 64, 3);
  gemm_nt3<<<g3, 256, 0, stream>>>(x, Wk, Wv, Wr, Kbuf, Vbuf, SRbuf,
                                   M_ROWS, C_DIM, C_DIM, 2);
  // 2) WKV recurrence (gather+scatter fused via scan_indices)
  dim3 gw(B_DIM, C_DIM / 256);
  wkv_kernel<<<gw, 256, 0, stream>>>(Kbuf, Vbuf, sidx, decay, first, Ybuf);
  // 3) LayerNorm + sigmoid gate (in place on Ybuf)
  ln_gate_kernel<<<M_ROWS, 256, 0, stream>>>(Ybuf, SRbuf, ln_g, ln_b);
  // 4) out = gated @ Wo^T
  dim3 g1(M_ROWS / 64, C_DIM / 64, 1);
  gemm_nt3<<<g1, 256, 0, stream>>>(Ybuf, Wo, Wo, Wo, out, out, out,
                                   M_ROWS, C_DIM, C_DIM, -1);
}

// Round 2
// 688.649 us; speedup vs baseline: 4.0330x; 4.0330x over previous
//
#include <hip/hip_runtime.h>
#include <cstddef>
#include <cstdint>

#define B_DIM 8
#define T_SEQ 4096
#define C_DIM 768
#define M_ROWS (B_DIM * T_SEQ)   // 32768
#define CC (C_DIM * C_DIM)       // 589824
#define NCH 32
#define CHL (T_SEQ / NCH)        // 128

using bf16x8 = __attribute__((ext_vector_type(8))) short;
using f32x4  = __attribute__((ext_vector_type(4))) float;

static __device__ __forceinline__ unsigned short f2bf(float f) {
  unsigned int u = __float_as_uint(f);
  return (unsigned short)((u + 0x7fffu + ((u >> 16) & 1u)) >> 16);
}
static __device__ __forceinline__ float bf2f(unsigned short s) {
  return __uint_as_float(((unsigned int)s) << 16);
}

static __device__ __forceinline__ void gload_lds16(const void* g, void* l) {
  __builtin_amdgcn_global_load_lds(
      (const __attribute__((address_space(1))) unsigned int*)g,
      (__attribute__((address_space(3))) unsigned int*)l, 16, 0, 0);
}

// ---------------------------------------------------------------------------
// Convert f32 -> (bf16 hi, bf16 lo) residual split, 4 elems/thread.
// ---------------------------------------------------------------------------
__global__ __launch_bounds__(256) void convert_split(
    const float4* __restrict__ x, ushort4* __restrict__ xh, ushort4* __restrict__ xl)
{
  int i = blockIdx.x * 256 + threadIdx.x;
  float4 v = x[i];
  ushort4 h, l;
  h.x = f2bf(v.x); l.x = f2bf(v.x - bf2f(h.x));
  h.y = f2bf(v.y); l.y = f2bf(v.y - bf2f(h.y));
  h.z = f2bf(v.z); l.z = f2bf(v.z - bf2f(h.z));
  h.w = f2bf(v.w); l.w = f2bf(v.w - bf2f(h.w));
  xh[i] = h; xl[i] = l;
}

// ---------------------------------------------------------------------------
// MFMA GEMM (NT): O[m,n] = sum_k A[m,k] * W[n,k].  M=32768, N=K=768.
// 128x128 tile, BK=32, 4 waves (2x2), 16x16x32 bf16 MFMA, 2-phase dbuf,
// global_load_lds width 16, [kblk][row] LDS layout (conflict-lite),
// bijective XCD swizzle. SPLIT: acc = Ah*Wh + Al*Wh + Ah*Wl.
// EPI 0: f32 store to (z ? O1 : O0).  EPI 1: sigmoid -> bf16 store to Ob.
// ---------------------------------------------------------------------------
template<bool SPLIT, int EPI>
__global__ __launch_bounds__(256, 2) void gemm_mfma(
    const short* __restrict__ Ah, const short* __restrict__ Al,
    const short* __restrict__ Whb, const short* __restrict__ Wlb,
    float* __restrict__ O0, float* __restrict__ O1,
    unsigned short* __restrict__ Ob)
{
  constexpr int NT = SPLIT ? 4 : 2;     // tiles per stage buffer
  __shared__ short lds[2 * NT * 4096];  // 64KB (split) / 32KB (plain)

  const int K = C_DIM;
  const int z = blockIdx.z;
  const short* __restrict__ Wh = Whb + (size_t)z * CC;
  const short* __restrict__ Wl = SPLIT ? (Wlb + (size_t)z * CC) : (const short*)nullptr;

  // XCD-aware swizzle: 1536 wgs/z, 8 XCDs, 192 per XCD (bijective).
  int f  = blockIdx.x + blockIdx.y * 6;
  int wg = (f & 7) * 192 + (f >> 3);
  const int n0 = (wg % 6) * 128;
  const int m0 = (wg / 6) * 128;

  const int tid  = threadIdx.x;
  const int lane = tid & 63, wave = tid >> 6;
  const int wr = wave >> 1, wc = wave & 1;
  const int lr = lane & 15, lk = lane >> 4;

  // slot s in [0,512): LDS shorts [s*8, s*8+8) hold row (s&127), k-chunk (s>>7)
  const int s1 = wave * 64 + lane;
  const int s2 = s1 + 256;
  const int r1 = s1 & 127, q1 = s1 >> 7;
  const int r2 = s2 & 127, q2 = s2 >> 7;

  auto stage = [&](int buf, int k0) {
    short* base = &lds[buf * NT * 4096];
    gload_lds16(Ah + (size_t)(m0 + r1) * K + k0 + q1 * 8, base + wave * 512);
    gload_lds16(Ah + (size_t)(m0 + r2) * K + k0 + q2 * 8, base + 2048 + wave * 512);
    gload_lds16(Wh + (size_t)(n0 + r1) * K + k0 + q1 * 8, base + 4096 + wave * 512);
    gload_lds16(Wh + (size_t)(n0 + r2) * K + k0 + q2 * 8, base + 4096 + 2048 + wave * 512);
    if (SPLIT) {
      gload_lds16(Al + (size_t)(m0 + r1) * K + k0 + q1 * 8, base + 8192 + wave * 512);
      gload_lds16(Al + (size_t)(m0 + r2) * K + k0 + q2 * 8, base + 8192 + 2048 + wave * 512);
      gload_lds16(Wl + (size_t)(n0 + r1) * K + k0 + q1 * 8, base + 12288 + wave * 512);
      gload_lds16(Wl + (size_t)(n0 + r2) * K + k0 + q2 * 8, base + 12288 + 2048 + wave * 512);
    }
  };

  f32x4 acc[4][4];
#pragma unroll
  for (int i = 0; i < 4; ++i)
#pragma unroll
    for (int j = 0; j < 4; ++j) acc[i][j] = (f32x4){0.f, 0.f, 0.f, 0.f};

  stage(0, 0);
  __syncthreads();   // drains vmcnt(0) -> buf0 staged

  int buf = 0;
  const int NKT = K / 32;  // 24
  for (int kt = 0; kt < NKT; ++kt) {
    if (kt + 1 < NKT) stage(buf ^ 1, (kt + 1) * 32);
    const short* base = &lds[buf * NT * 4096];
    bf16x8 ah[4], bh[4], al[4], bl[4];
#pragma unroll
    for (int mi = 0; mi < 4; ++mi) {
      ah[mi] = *(const bf16x8*)(base + lk * 1024 + (wr * 64 + mi * 16 + lr) * 8);
      bh[mi] = *(const bf16x8*)(base + 4096 + lk * 1024 + (wc * 64 + mi * 16 + lr) * 8);
      if (SPLIT) {
        al[mi] = *(const bf16x8*)(base + 8192 + lk * 1024 + (wr * 64 + mi * 16 + lr) * 8);
        bl[mi] = *(const bf16x8*)(base + 12288 + lk * 1024 + (wc * 64 + mi * 16 + lr) * 8);
      }
    }
#pragma unroll
    for (int mi = 0; mi < 4; ++mi)
#pragma unroll
      for (int ni = 0; ni < 4; ++ni) {
        acc[mi][ni] = __builtin_amdgcn_mfma_f32_16x16x32_bf16(ah[mi], bh[ni], acc[mi][ni], 0, 0, 0);
        if (SPLIT) {
          acc[mi][ni] = __builtin_amdgcn_mfma_f32_16x16x32_bf16(al[mi], bh[ni], acc[mi][ni], 0, 0, 0);
          acc[mi][ni] = __builtin_amdgcn_mfma_f32_16x16x32_bf16(ah[mi], bl[ni], acc[mi][ni], 0, 0, 0);
        }
      }
    __syncthreads();   // waits vmcnt(0): next buffer staged; lgkm drained
    buf ^= 1;
  }

  float* __restrict__ O = (EPI == 0) ? (z ? O1 : O0) : (float*)nullptr;
#pragma unroll
  for (int mi = 0; mi < 4; ++mi)
#pragma unroll
    for (int ni = 0; ni < 4; ++ni) {
      const int row = m0 + wr * 64 + mi * 16 + lk * 4;
      const int col = n0 + wc * 64 + ni * 16 + lr;
#pragma unroll
      for (int j = 0; j < 4; ++j) {
        float v = acc[mi][ni][j];
        if (EPI == 1) {
          float s = 1.f / (1.f + __expf(-v));
          Ob[(size_t)(row + j) * C_DIM + col] = f2bf(s);
        } else {
          O[(size_t)(row + j) * C_DIM + col] = v;
        }
      }
    }
}

// ---------------------------------------------------------------------------
// WKV chunk-parallel scan. Pass 1: per-(b,c,chunk) local transition triple.
// ---------------------------------------------------------------------------
#define P1_LOAD(kk_, vv_, base_)                                  \
  _Pragma("unroll") for (int j = 0; j < 8; ++j) {                 \
    int r_ = si[(base_) + j];                                     \
    kk_[j] = Kb[(size_t)r_ * C_DIM];                              \
    vv_[j] = Vb[(size_t)r_ * C_DIM];                              \
  }
#define P1_COMP(kk_, vv_)                                         \
  _Pragma("unroll") for (int j = 0; j < 8; ++j) {                 \
    float kt = kk_[j], vt = vv_[j];                               \
    float ww2 = w + pp; float p2 = fmaxf(ww2, kt);                \
    float e1b = __expf(ww2 - p2), e2b = __expf(kt - p2);          \
    aa = e1b * aa + e2b * vt; bb = e1b * bb + e2b; pp = p2;       \
  }

__global__ __launch_bounds__(256) void wkv_pass1(
    const float* __restrict__ Kin, const float* __restrict__ Vin,
    const int* __restrict__ sidx, const float* __restrict__ decay,
    float* __restrict__ aL, float* __restrict__ bL, float* __restrict__ pL)
{
  __shared__ int si[CHL];
  const int tid = threadIdx.x;
  const int ch = blockIdx.x, b = blockIdx.z;
  const int c = blockIdx.y * 256 + tid;
  if (tid < CHL) si[tid] = sidx[ch * CHL + tid];
  __syncthreads();
  const float w = decay[c] * (1.0f / (float)T_SEQ);
  const float* Kb = Kin + (size_t)b * T_SEQ * C_DIM + c;
  const float* Vb = Vin + (size_t)b * T_SEQ * C_DIM + c;
  float aa = 0.f, bb = 0.f, pp = -1e38f;
  float kA[8], vA[8], kB[8], vB[8];
  P1_LOAD(kA, vA, 0)
  for (int t0 = 0; t0 < CHL; t0 += 16) {
    P1_LOAD(kB, vB, t0 + 8)
    P1_COMP(kA, vA)
    if (t0 + 16 < CHL) { P1_LOAD(kA, vA, t0 + 16) }
    P1_COMP(kB, vB)
  }
  const int idx = (b * C_DIM + c) * NCH + ch;
  aL[idx] = aa; bL[idx] = bb; pL[idx] = pp;
}

// Serial scan over chunks per (b,c): S_in(ch+1) = merge(decay(S_in(ch)), local(ch)).
__global__ __launch_bounds__(256) void wkv_scan(
    const float* __restrict__ aL, const float* __restrict__ bL,
    const float* __restrict__ pL,
    float* __restrict__ aI, float* __restrict__ bI, float* __restrict__ pI,
    const float* __restrict__ decay)
{
  const int g = blockIdx.x * 256 + threadIdx.x;  // 0..6143 = b*C + c
  const int c = g % C_DIM;
  const float wL = decay[c] * ((float)CHL / (float)T_SEQ);
  float aa = 0.f, bb = 0.f, pp = -1e38f;
  const int base = g * NCH;
  for (int ch = 0; ch < NCH; ++ch) {
    aI[base + ch] = aa; bI[base + ch] = bb; pI[base + ch] = pp;
    float p1 = pp + wL;
    float p2 = pL[base + ch];
    float p  = fmaxf(p1, p2);
    float e1 = __expf(p1 - p), e2 = __expf(p2 - p);
    aa = e1 * aa + e2 * aL[base + ch];
    bb = e1 * bb + e2 * bL[base + ch];
    pp = p;
  }
}

// Pass 2: replay chunk with correct incoming state; emit y scattered to
// natural order (fuses gather by scan_indices + inverse-permute).
#define P2_LOAD(rr_, kk_, vv_, base_)                             \
  _Pragma("unroll") for (int j = 0; j < 8; ++j) {                 \
    int r_ = si[(base_) + j];                                     \
    rr_[j] = r_;                                                  \
    kk_[j] = Kb[(size_t)r_ * C_DIM];                              \
    vv_[j] = Vb[(size_t)r_ * C_DIM];                              \
  }
#define P2_COMP(rr_, kk_, vv_)                                    \
  _Pragma("unroll") for (int j = 0; j < 8; ++j) {                 \
    float kt = kk_[j], vt = vv_[j];                               \
    float ww = u + kt; float p = fmaxf(pp, ww);                   \
    float e1 = __expf(pp - p), e2 = __expf(ww - p);               \
    Yb[(size_t)rr_[j] * C_DIM] = (e1 * aa + e2 * vt) / (e1 * bb + e2); \
    float ww2 = w + pp; float p2 = fmaxf(ww2, kt);                \
    float e1b = __expf(ww2 - p2), e2b = __expf(kt - p2);          \
    aa = e1b * aa + e2b * vt; bb = e1b * bb + e2b; pp = p2;       \
  }

__global__ __launch_bounds__(256) void wkv_pass2(
    const float* __restrict__ Kin, const float* __restrict__ Vin,
    const int* __restrict__ sidx,
    const float* __restrict__ decay, const float* __restrict__ first,
    const float* __restrict__ aI, const float* __restrict__ bI,
    const float* __restrict__ pI, float* __restrict__ Y)
{
  __shared__ int si[CHL];
  const int tid = threadIdx.x;
  const int ch = blockIdx.x, b = blockIdx.z;
  const int c = blockIdx.y * 256 + tid;
  if (tid < CHL) si[tid] = sidx[ch * CHL + tid];
  __syncthreads();
  const float w = decay[c] * (1.0f / (float)T_SEQ);
  const float u = first[c] * (1.0f / (float)T_SEQ);
  const float* Kb = Kin + (size_t)b * T_SEQ * C_DIM + c;
  const float* Vb = Vin + (size_t)b * T_SEQ * C_DIM + c;
  float* Yb = Y + (size_t)b * T_SEQ * C_DIM + c;
  const int idx = (b * C_DIM + c) * NCH + ch;
  float aa = aI[idx], bb = bI[idx], pp = pI[idx];
  int rA[8], rB[8]; float kA[8], vA[8], kB[8], vB[8];
  P2_LOAD(rA, kA, vA, 0)
  for (int t0 = 0; t0 < CHL; t0 += 16) {
    P2_LOAD(rB, kB, vB, t0 + 8)
    P2_COMP(rA, kA, vA)
    if (t0 + 16 < CHL) { P2_LOAD(rA, kA, vA, t0 + 16) }
    P2_COMP(rB, kB, vB)
  }
}

// ---------------------------------------------------------------------------
// Row LayerNorm over C + sigmoid gate; writes bf16 operand for output GEMM.
// ---------------------------------------------------------------------------
__global__ __launch_bounds__(256) void ln_gate(
    const float* __restrict__ Y, const unsigned short* __restrict__ SR,
    const float* __restrict__ gam, const float* __restrict__ bet,
    unsigned short* __restrict__ G)
{
  const size_t row = blockIdx.x;
  const float* x = Y + row * C_DIM;
  const unsigned short* sr = SR + row * C_DIM;
  unsigned short* go = G + row * C_DIM;
  const int tid = threadIdx.x;

  float vals[3];
  float s = 0.f, s2 = 0.f;
#pragma unroll
  for (int j = 0; j < 3; ++j) {
    float v = x[tid + j * 256];
    vals[j] = v;
    s += v; s2 += v * v;
  }
#pragma unroll
  for (int off = 32; off >= 1; off >>= 1) {
    s  += __shfl_xor(s, off, 64);
    s2 += __shfl_xor(s2, off, 64);
  }
  __shared__ float red[8];
  const int wid = tid >> 6;
  if ((tid & 63) == 0) { red[wid] = s; red[wid + 4] = s2; }
  __syncthreads();
  s  = red[0] + red[1] + red[2] + red[3];
  s2 = red[4] + red[5] + red[6] + red[7];

  const float mu   = s * (1.f / (float)C_DIM);
  const float var  = s2 * (1.f / (float)C_DIM) - mu * mu;
  const float rsig = rsqrtf(var + 1e-5f);

#pragma unroll
  for (int j = 0; j < 3; ++j) {
    const int cc = tid + j * 256;
    float yv = (vals[j] - mu) * rsig * gam[cc] + bet[cc];
    go[cc] = f2bf(yv * bf2f(sr[cc]));
  }
}

// ---------------------------------------------------------------------------
extern "C" void kernel_launch(void* const* d_in, const int* in_sizes, int n_in,
                              void* d_out, int out_size, void* d_ws, size_t ws_size,
                              hipStream_t stream) {
  const float* x     = (const float*)d_in[0];
  const int*   sidx  = (const int*)  d_in[1];
  const float* decay = (const float*)d_in[2];
  const float* first = (const float*)d_in[3];
  const float* Wk    = (const float*)d_in[4];
  const float* Wv    = (const float*)d_in[5];
  const float* Wr    = (const float*)d_in[6];
  const float* Wo    = (const float*)d_in[7];
  const float* ln_g  = (const float*)d_in[8];
  const float* ln_b  = (const float*)d_in[9];
  float* out = (float*)d_out;

  const size_t NE = (size_t)M_ROWS * C_DIM;  // 25165824
  // Workspace layout (366.5 MB total, with aliasing):
  short* x_hi = (short*)d_ws;                       // NE bf16
  short* x_lo = x_hi + NE;                          // NE bf16
  float* Ybuf = (float*)x_hi;                       // alias: Y after GEMMs done
  short* Whs  = x_lo + NE;                          // 4*CC bf16 (Wk,Wv,Wr,Wo hi)
  short* Wls  = Whs + 4 * CC;                       // 4*CC bf16 (lo)
  float* Kbuf = (float*)(Wls + 4 * CC);             // NE f32
  unsigned short* Gbuf = (unsigned short*)Kbuf;     // alias: G after pass2 done
  float* Vbuf = Kbuf + NE;                          // NE f32
  unsigned short* SRb = (unsigned short*)(Vbuf + NE); // NE bf16
  float* aL = (float*)(SRb + NE);                   // 6 x 196608 f32 states
  float* bL = aL + 196608;
  float* pL = bL + 196608;
  float* aI = pL + 196608;
  float* bI = aI + 196608;
  float* pI = bI + 196608;

  // 1) hi/lo splits of x and the 4 weight matrices
  convert_split<<<24576, 256, 0, stream>>>((const float4*)x, (ushort4*)x_hi, (ushort4*)x_lo);
  convert_split<<<576, 256, 0, stream>>>((const float4*)Wk, (ushort4*)(Whs + 0 * (size_t)CC), (ushort4*)(Wls + 0 * (size_t)CC));
  convert_split<<<576, 256, 0, stream>>>((const float4*)Wv, (ushort4*)(Whs + 1 * (size_t)CC), (ushort4*)(Wls + 1 * (size_t)CC));
  convert_split<<<576, 256, 0, stream>>>((const float4*)Wr, (ushort4*)(Whs + 2 * (size_t)CC), (ushort4*)(Wls + 2 * (size_t)CC));
  convert_split<<<576, 256, 0, stream>>>((const float4*)Wo, (ushort4*)(Whs + 3 * (size_t)CC), (ushort4*)(Wls + 3 * (size_t)CC));

  // 2) k, v via split-precision MFMA GEMM (z=0 -> K, z=1 -> V)
  gemm_mfma<true, 0><<<dim3(6, 256, 2), 256, 0, stream>>>(
      x_hi, x_lo, Whs, Wls, Kbuf, Vbuf, nullptr);
  // 3) sr = sigmoid(x @ Wr^T), plain bf16, stored bf16
  gemm_mfma<false, 1><<<dim3(6, 256, 1), 256, 0, stream>>>(
      x_hi, nullptr, Whs + 2 * (size_t)CC, nullptr, nullptr, nullptr, SRb);

  // 4) WKV: chunk transitions -> serial chunk scan -> replay with y output
  wkv_pass1<<<dim3(NCH, 3, B_DIM), 256, 0, stream>>>(Kbuf, Vbuf, sidx, decay, aL, bL, pL);
  wkv_scan<<<24, 256, 0, stream>>>(aL, bL, pL, aI, bI, pI, decay);
  wkv_pass2<<<dim3(NCH, 3, B_DIM), 256, 0, stream>>>(Kbuf, Vbuf, sidx, decay, first,
                                                     aI, bI, pI, Ybuf);
  // 5) LayerNorm + gate -> bf16 GEMM operand (G aliases K region; K dead now)
  ln_gate<<<M_ROWS, 256, 0, stream>>>(Ybuf, SRb, ln_g, ln_b, Gbuf);
  // 6) out = G @ Wo^T (plain bf16 -> f32)
  gemm_mfma<false, 0><<<dim3(6, 256, 1), 256, 0, stream>>>(
      (const short*)Gbuf, nullptr, Whs + 3 * (size_t)CC, nullptr, out, nullptr, nullptr);
}

// Round 3
// 503.375 us; speedup vs baseline: 5.5174x; 1.3681x over previous
//
#include <hip/hip_runtime.h>
#include <cstddef>
#include <cstdint>

#define B_DIM 8
#define T_SEQ 4096
#define C_DIM 768
#define M_ROWS (B_DIM * T_SEQ)   // 32768
#define CC (C_DIM * C_DIM)       // 589824
#define NCH 32
#define CHL (T_SEQ / NCH)        // 128

using bf16x8 = __attribute__((ext_vector_type(8))) short;
using f32x4  = __attribute__((ext_vector_type(4))) float;

static __device__ __forceinline__ unsigned short f2bf(float f) {
  unsigned int u = __float_as_uint(f);
  return (unsigned short)((u + 0x7fffu + ((u >> 16) & 1u)) >> 16);
}
static __device__ __forceinline__ float bf2f(unsigned short s) {
  return __uint_as_float(((unsigned int)s) << 16);
}

static __device__ __forceinline__ void gload_lds16(const void* g, void* l) {
  __builtin_amdgcn_global_load_lds(
      (const __attribute__((address_space(1))) unsigned int*)g,
      (__attribute__((address_space(3))) unsigned int*)l, 16, 0, 0);
}

// ---------------------------------------------------------------------------
// f32 -> bf16 (round-nearest-even), 4 elems/thread.
// ---------------------------------------------------------------------------
__global__ __launch_bounds__(256) void convert_hi(
    const float4* __restrict__ x, ushort4* __restrict__ xh)
{
  int i = blockIdx.x * 256 + threadIdx.x;
  float4 v = x[i];
  ushort4 h;
  h.x = f2bf(v.x); h.y = f2bf(v.y); h.z = f2bf(v.z); h.w = f2bf(v.w);
  xh[i] = h;
}

// ---------------------------------------------------------------------------
// MFMA GEMM (NT): O[m,n] = sum_k A[m,k] * W[n,k].  M=32768, N=K=768.
// 128x128 tile, BK=32, 4 waves (2x2), 16x16x32 bf16 MFMA, 2-phase dbuf,
// global_load_lds width 16, bijective XCD swizzle. 32KB LDS.
// MODE 0 (kvr): W = Wbase + z*CC; z=0 -> f32 OK, z=1 -> f32 OV,
//               z=2 -> sigmoid -> bf16 OSR.
// MODE 1 (out): W = Wbase; f32 Oout.
// ---------------------------------------------------------------------------
template<int MODE>
__global__ __launch_bounds__(256, 4) void gemm_plain(
    const short* __restrict__ A, const short* __restrict__ Wbase,
    float* __restrict__ OK, float* __restrict__ OV,
    unsigned short* __restrict__ OSR, float* __restrict__ Oout)
{
  __shared__ short lds[2 * 2 * 4096];   // 32 KB: 2 bufs x (A-tile | W-tile)

  const int K = C_DIM;
  const int z = (MODE == 0) ? blockIdx.z : 0;
  const short* __restrict__ W = (MODE == 0) ? (Wbase + (size_t)z * CC) : Wbase;

  // XCD-aware swizzle: 1536 wgs per z, 8 XCDs, 192 each (bijective).
  int f  = blockIdx.x + blockIdx.y * 6;
  int wg = (f & 7) * 192 + (f >> 3);
  const int n0 = (wg % 6) * 128;
  const int m0 = (wg / 6) * 128;

  const int tid  = threadIdx.x;
  const int lane = tid & 63, wave = tid >> 6;
  const int wr = wave >> 1, wc = wave & 1;
  const int lr = lane & 15, lk = lane >> 4;

  // staging slot s in [0,512): shorts [s*8,s*8+8) = row (s&127), k-chunk (s>>7)
  const int s1 = wave * 64 + lane;
  const int s2 = s1 + 256;
  const int r1 = s1 & 127, q1 = s1 >> 7;
  const int r2 = s2 & 127, q2 = s2 >> 7;

  auto stage = [&](int buf, int k0) {
    short* base = &lds[buf * 8192];
    gload_lds16(A + (size_t)(m0 + r1) * K + k0 + q1 * 8, base + wave * 512);
    gload_lds16(A + (size_t)(m0 + r2) * K + k0 + q2 * 8, base + 2048 + wave * 512);
    gload_lds16(W + (size_t)(n0 + r1) * K + k0 + q1 * 8, base + 4096 + wave * 512);
    gload_lds16(W + (size_t)(n0 + r2) * K + k0 + q2 * 8, base + 4096 + 2048 + wave * 512);
  };

  f32x4 acc[4][4];
#pragma unroll
  for (int i = 0; i < 4; ++i)
#pragma unroll
    for (int j = 0; j < 4; ++j) acc[i][j] = (f32x4){0.f, 0.f, 0.f, 0.f};

  stage(0, 0);
  __syncthreads();

  int buf = 0;
  const int NKT = K / 32;  // 24
  for (int kt = 0; kt < NKT; ++kt) {
    if (kt + 1 < NKT) stage(buf ^ 1, (kt + 1) * 32);
    const short* base = &lds[buf * 8192];
    bf16x8 ah[4], bh[4];
#pragma unroll
    for (int mi = 0; mi < 4; ++mi) {
      ah[mi] = *(const bf16x8*)(base + lk * 1024 + (wr * 64 + mi * 16 + lr) * 8);
      bh[mi] = *(const bf16x8*)(base + 4096 + lk * 1024 + (wc * 64 + mi * 16 + lr) * 8);
    }
#pragma unroll
    for (int mi = 0; mi < 4; ++mi)
#pragma unroll
      for (int ni = 0; ni < 4; ++ni)
        acc[mi][ni] = __builtin_amdgcn_mfma_f32_16x16x32_bf16(ah[mi], bh[ni], acc[mi][ni], 0, 0, 0);
    __syncthreads();
    buf ^= 1;
  }

  float* __restrict__ O =
      (MODE == 1) ? Oout : (z == 0 ? OK : (z == 1 ? OV : nullptr));
#pragma unroll
  for (int mi = 0; mi < 4; ++mi)
#pragma unroll
    for (int ni = 0; ni < 4; ++ni) {
      const int row = m0 + wr * 64 + mi * 16 + lk * 4;
      const int col = n0 + wc * 64 + ni * 16 + lr;
#pragma unroll
      for (int j = 0; j < 4; ++j) {
        float v = acc[mi][ni][j];
        if (MODE == 0 && z == 2) {
          float s = 1.f / (1.f + __expf(-v));
          OSR[(size_t)(row + j) * C_DIM + col] = f2bf(s);
        } else {
          O[(size_t)(row + j) * C_DIM + col] = v;
        }
      }
    }
}

// ---------------------------------------------------------------------------
// WKV chunk-parallel scan. Pass 1: per-(b,c,chunk) local transition triple.
// ---------------------------------------------------------------------------
#define P1_LOAD(kk_, vv_, base_)                                  \
  _Pragma("unroll") for (int j = 0; j < 8; ++j) {                 \
    int r_ = si[(base_) + j];                                     \
    kk_[j] = Kb[(size_t)r_ * C_DIM];                              \
    vv_[j] = Vb[(size_t)r_ * C_DIM];                              \
  }
#define P1_COMP(kk_, vv_)                                         \
  _Pragma("unroll") for (int j = 0; j < 8; ++j) {                 \
    float kt = kk_[j], vt = vv_[j];                               \
    float ww2 = w + pp; float p2 = fmaxf(ww2, kt);                \
    float e1b = __expf(ww2 - p2), e2b = __expf(kt - p2);          \
    aa = e1b * aa + e2b * vt; bb = e1b * bb + e2b; pp = p2;       \
  }

__global__ __launch_bounds__(256) void wkv_pass1(
    const float* __restrict__ Kin, const float* __restrict__ Vin,
    const int* __restrict__ sidx, const float* __restrict__ decay,
    float* __restrict__ aL, float* __restrict__ bL, float* __restrict__ pL)
{
  __shared__ int si[CHL];
  const int tid = threadIdx.x;
  const int ch = blockIdx.x, b = blockIdx.z;
  const int c = blockIdx.y * 256 + tid;
  if (tid < CHL) si[tid] = sidx[ch * CHL + tid];
  __syncthreads();
  const float w = decay[c] * (1.0f / (float)T_SEQ);
  const float* Kb = Kin + (size_t)b * T_SEQ * C_DIM + c;
  const float* Vb = Vin + (size_t)b * T_SEQ * C_DIM + c;
  float aa = 0.f, bb = 0.f, pp = -1e38f;
  float kA[8], vA[8], kB[8], vB[8];
  P1_LOAD(kA, vA, 0)
  for (int t0 = 0; t0 < CHL; t0 += 16) {
    P1_LOAD(kB, vB, t0 + 8)
    P1_COMP(kA, vA)
    if (t0 + 16 < CHL) { P1_LOAD(kA, vA, t0 + 16) }
    P1_COMP(kB, vB)
  }
  const int idx = (b * C_DIM + c) * NCH + ch;
  aL[idx] = aa; bL[idx] = bb; pL[idx] = pp;
}

// Serial scan over chunks per (b,c).
__global__ __launch_bounds__(256) void wkv_scan(
    const float* __restrict__ aL, const float* __restrict__ bL,
    const float* __restrict__ pL,
    float* __restrict__ aI, float* __restrict__ bI, float* __restrict__ pI,
    const float* __restrict__ decay)
{
  const int g = blockIdx.x * 256 + threadIdx.x;  // 0..6143 = b*C + c
  const int c = g % C_DIM;
  const float wL = decay[c] * ((float)CHL / (float)T_SEQ);
  float aa = 0.f, bb = 0.f, pp = -1e38f;
  const int base = g * NCH;
  for (int ch = 0; ch < NCH; ++ch) {
    aI[base + ch] = aa; bI[base + ch] = bb; pI[base + ch] = pp;
    float p1 = pp + wL;
    float p2 = pL[base + ch];
    float p  = fmaxf(p1, p2);
    float e1 = __expf(p1 - p), e2 = __expf(p2 - p);
    aa = e1 * aa + e2 * aL[base + ch];
    bb = e1 * bb + e2 * bL[base + ch];
    pp = p;
  }
}

// Pass 2: replay chunk with incoming state; y scattered to natural order.
#define P2_LOAD(rr_, kk_, vv_, base_)                             \
  _Pragma("unroll") for (int j = 0; j < 8; ++j) {                 \
    int r_ = si[(base_) + j];                                     \
    rr_[j] = r_;                                                  \
    kk_[j] = Kb[(size_t)r_ * C_DIM];                              \
    vv_[j] = Vb[(size_t)r_ * C_DIM];                              \
  }
#define P2_COMP(rr_, kk_, vv_)                                    \
  _Pragma("unroll") for (int j = 0; j < 8; ++j) {                 \
    float kt = kk_[j], vt = vv_[j];                               \
    float ww = u + kt; float p = fmaxf(pp, ww);                   \
    float e1 = __expf(pp - p), e2 = __expf(ww - p);               \
    Yb[(size_t)rr_[j] * C_DIM] = (e1 * aa + e2 * vt) / (e1 * bb + e2); \
    float ww2 = w + pp; float p2 = fmaxf(ww2, kt);                \
    float e1b = __expf(ww2 - p2), e2b = __expf(kt - p2);          \
    aa = e1b * aa + e2b * vt; bb = e1b * bb + e2b; pp = p2;       \
  }

__global__ __launch_bounds__(256) void wkv_pass2(
    const float* __restrict__ Kin, const float* __restrict__ Vin,
    const int* __restrict__ sidx,
    const float* __restrict__ decay, const float* __restrict__ first,
    const float* __restrict__ aI, const float* __restrict__ bI,
    const float* __restrict__ pI, float* __restrict__ Y)
{
  __shared__ int si[CHL];
  const int tid = threadIdx.x;
  const int ch = blockIdx.x, b = blockIdx.z;
  const int c = blockIdx.y * 256 + tid;
  if (tid < CHL) si[tid] = sidx[ch * CHL + tid];
  __syncthreads();
  const float w = decay[c] * (1.0f / (float)T_SEQ);
  const float u = first[c] * (1.0f / (float)T_SEQ);
  const float* Kb = Kin + (size_t)b * T_SEQ * C_DIM + c;
  const float* Vb = Vin + (size_t)b * T_SEQ * C_DIM + c;
  float* Yb = Y + (size_t)b * T_SEQ * C_DIM + c;
  const int idx = (b * C_DIM + c) * NCH + ch;
  float aa = aI[idx], bb = bI[idx], pp = pI[idx];
  int rA[8], rB[8]; float kA[8], vA[8], kB[8], vB[8];
  P2_LOAD(rA, kA, vA, 0)
  for (int t0 = 0; t0 < CHL; t0 += 16) {
    P2_LOAD(rB, kB, vB, t0 + 8)
    P2_COMP(rA, kA, vA)
    if (t0 + 16 < CHL) { P2_LOAD(rA, kA, vA, t0 + 16) }
    P2_COMP(rB, kB, vB)
  }
}

// ---------------------------------------------------------------------------
// Row LayerNorm over C + sigmoid gate; writes bf16 operand for output GEMM.
// ---------------------------------------------------------------------------
__global__ __launch_bounds__(256) void ln_gate(
    const float* __restrict__ Y, const unsigned short* __restrict__ SR,
    const float* __restrict__ gam, const float* __restrict__ bet,
    unsigned short* __restrict__ G)
{
  const size_t row = blockIdx.x;
  const float* x = Y + row * C_DIM;
  const unsigned short* sr = SR + row * C_DIM;
  unsigned short* go = G + row * C_DIM;
  const int tid = threadIdx.x;

  float vals[3];
  float s = 0.f, s2 = 0.f;
#pragma unroll
  for (int j = 0; j < 3; ++j) {
    float v = x[tid + j * 256];
    vals[j] = v;
    s += v; s2 += v * v;
  }
#pragma unroll
  for (int off = 32; off >= 1; off >>= 1) {
    s  += __shfl_xor(s, off, 64);
    s2 += __shfl_xor(s2, off, 64);
  }
  __shared__ float red[8];
  const int wid = tid >> 6;
  if ((tid & 63) == 0) { red[wid] = s; red[wid + 4] = s2; }
  __syncthreads();
  s  = red[0] + red[1] + red[2] + red[3];
  s2 = red[4] + red[5] + red[6] + red[7];

  const float mu   = s * (1.f / (float)C_DIM);
  const float var  = s2 * (1.f / (float)C_DIM) - mu * mu;
  const float rsig = rsqrtf(var + 1e-5f);

#pragma unroll
  for (int j = 0; j < 3; ++j) {
    const int cc = tid + j * 256;
    float yv = (vals[j] - mu) * rsig * gam[cc] + bet[cc];
    go[cc] = f2bf(yv * bf2f(sr[cc]));
  }
}

// ---------------------------------------------------------------------------
extern "C" void kernel_launch(void* const* d_in, const int* in_sizes, int n_in,
                              void* d_out, int out_size, void* d_ws, size_t ws_size,
                              hipStream_t stream) {
  const float* x     = (const float*)d_in[0];
  const int*   sidx  = (const int*)  d_in[1];
  const float* decay = (const float*)d_in[2];
  const float* first = (const float*)d_in[3];
  const float* Wk    = (const float*)d_in[4];
  const float* Wv    = (const float*)d_in[5];
  const float* Wr    = (const float*)d_in[6];
  const float* Wo    = (const float*)d_in[7];
  const float* ln_g  = (const float*)d_in[8];
  const float* ln_b  = (const float*)d_in[9];
  float* out = (float*)d_out;

  const size_t NE = (size_t)M_ROWS * C_DIM;  // 25165824
  // Workspace layout (~362 MB):
  short* Whs  = (short*)d_ws;                    // 4*CC bf16
  float* Ybuf = (float*)(Whs + 4 * (size_t)CC);  // NE f32 (x_hi aliases front)
  short* x_hi = (short*)Ybuf;                    // NE bf16 (dead before Y written)
  float* Kbuf = Ybuf + NE;                       // NE f32
  unsigned short* Gbuf = (unsigned short*)Kbuf;  // alias: after K dead
  float* Vbuf = Kbuf + NE;                       // NE f32
  unsigned short* SRb = (unsigned short*)(Vbuf + NE); // NE bf16
  float* aL = (float*)(SRb + NE);                // 6 x 196608 f32
  float* bL = aL + 196608;
  float* pL = bL + 196608;
  float* aI = pL + 196608;
  float* bI = aI + 196608;
  float* pI = bI + 196608;

  // 1) bf16 conversions
  convert_hi<<<24576, 256, 0, stream>>>((const float4*)x, (ushort4*)x_hi);
  convert_hi<<<576, 256, 0, stream>>>((const float4*)Wk, (ushort4*)(Whs + 0 * (size_t)CC));
  convert_hi<<<576, 256, 0, stream>>>((const float4*)Wv, (ushort4*)(Whs + 1 * (size_t)CC));
  convert_hi<<<576, 256, 0, stream>>>((const float4*)Wr, (ushort4*)(Whs + 2 * (size_t)CC));
  convert_hi<<<576, 256, 0, stream>>>((const float4*)Wo, (ushort4*)(Whs + 3 * (size_t)CC));

  // 2) k, v (f32 out), sr = sigmoid(r) (bf16 out) in one dispatch
  gemm_plain<0><<<dim3(6, 256, 3), 256, 0, stream>>>(
      x_hi, Whs, Kbuf, Vbuf, SRb, nullptr);

  // 3) WKV: chunk transitions -> serial chunk scan -> replay with y output
  wkv_pass1<<<dim3(NCH, 3, B_DIM), 256, 0, stream>>>(Kbuf, Vbuf, sidx, decay, aL, bL, pL);
  wkv_scan<<<24, 256, 0, stream>>>(aL, bL, pL, aI, bI, pI, decay);
  wkv_pass2<<<dim3(NCH, 3, B_DIM), 256, 0, stream>>>(Kbuf, Vbuf, sidx, decay, first,
                                                     aI, bI, pI, Ybuf);
  // 4) LayerNorm + gate -> bf16 GEMM operand (G aliases K; K dead now)
  ln_gate<<<M_ROWS, 256, 0, stream>>>(Ybuf, SRb, ln_g, ln_b, Gbuf);
  // 5) out = G @ Wo^T
  gemm_plain<1><<<dim3(6, 256, 1), 256, 0, stream>>>(
      (const short*)Gbuf, Whs + 3 * (size_t)CC, nullptr, nullptr, nullptr, out);
}

// Round 4
// 494.438 us; speedup vs baseline: 5.6171x; 1.0181x over previous
//
#include <hip/hip_runtime.h>
#include <cstddef>
#include <cstdint>

#define B_DIM 8
#define T_SEQ 4096
#define C_DIM 768
#define M_ROWS (B_DIM * T_SEQ)   // 32768
#define CC (C_DIM * C_DIM)       // 589824
#define NCH 32
#define CHL (T_SEQ / NCH)        // 128

using bf16x8 = __attribute__((ext_vector_type(8))) short;
using f32x4  = __attribute__((ext_vector_type(4))) float;

static __device__ __forceinline__ unsigned short f2bf(float f) {
  unsigned int u = __float_as_uint(f);
  return (unsigned short)((u + 0x7fffu + ((u >> 16) & 1u)) >> 16);
}
static __device__ __forceinline__ float bf2f(unsigned short s) {
  return __uint_as_float(((unsigned int)s) << 16);
}

static __device__ __forceinline__ void gload_lds16(const void* g, void* l) {
  __builtin_amdgcn_global_load_lds(
      (const __attribute__((address_space(1))) unsigned int*)g,
      (__attribute__((address_space(3))) unsigned int*)l, 16, 0, 0);
}

// ---------------------------------------------------------------------------
// f32 -> bf16 converts. convert_x: bulk x. convert_w4: 4 weight mats fused.
// ---------------------------------------------------------------------------
__global__ __launch_bounds__(256) void convert_x(
    const float4* __restrict__ x, ushort4* __restrict__ xh)
{
  int i = blockIdx.x * 256 + threadIdx.x;
  float4 v = x[i];
  ushort4 h;
  h.x = f2bf(v.x); h.y = f2bf(v.y); h.z = f2bf(v.z); h.w = f2bf(v.w);
  xh[i] = h;
}

__global__ __launch_bounds__(256) void convert_w4(
    const float4* __restrict__ w0, const float4* __restrict__ w1,
    const float4* __restrict__ w2, const float4* __restrict__ w3,
    ushort4* __restrict__ dst)
{
  const int z = blockIdx.y;
  const float4* __restrict__ src = (z == 0) ? w0 : (z == 1) ? w1 : (z == 2) ? w2 : w3;
  int i = blockIdx.x * 256 + threadIdx.x;
  float4 v = src[i];
  ushort4 h;
  h.x = f2bf(v.x); h.y = f2bf(v.y); h.z = f2bf(v.z); h.w = f2bf(v.w);
  dst[(size_t)z * (CC / 4) + i] = h;
}

// ---------------------------------------------------------------------------
// MFMA GEMM (NT): O[m,n] = sum_k A[m,k] * W[n,k].  M=32768, N=K=768.
// 128x128 tile, BK=32, 4 waves (2x2), 16x16x32 bf16 MFMA.
// 3-deep LDS pipeline + counted vmcnt(4): stage(t+2) issued at iter t,
// only stage(t) awaited -> DMA latency hides under 2 compute steps (T4).
// Raw s_barrier (no implicit vmcnt(0) drain), sched_barrier(0) fences.
// MODE 0 (kvr): W = Wbase + z*CC; z=0 -> f32 OK, z=1 -> f32 OV,
//               z=2 -> sigmoid -> bf16 OSR.
// MODE 1 (out): W = Wbase; f32 Oout.
// ---------------------------------------------------------------------------
template<int MODE>
__global__ __launch_bounds__(256, 3) void gemm_pipe(
    const short* __restrict__ A, const short* __restrict__ Wbase,
    float* __restrict__ OK, float* __restrict__ OV,
    unsigned short* __restrict__ OSR, float* __restrict__ Oout)
{
  __shared__ short lds[3 * 2 * 4096];   // 48 KB: 3 bufs x (A-tile | W-tile)

  const int K = C_DIM;
  const int z = (MODE == 0) ? blockIdx.z : 0;
  const short* __restrict__ W = (MODE == 0) ? (Wbase + (size_t)z * CC) : Wbase;

  // XCD-aware swizzle: 1536 wgs per z, 8 XCDs, 192 each (bijective).
  int f  = blockIdx.x + blockIdx.y * 6;
  int wg = (f & 7) * 192 + (f >> 3);
  const int n0 = (wg % 6) * 128;
  const int m0 = (wg / 6) * 128;

  const int tid  = threadIdx.x;
  const int lane = tid & 63, wave = tid >> 6;
  const int wr = wave >> 1, wc = wave & 1;
  const int lr = lane & 15, lk = lane >> 4;

  // staging slot s in [0,512): shorts [s*8,s*8+8) = row (s&127), k-chunk (s>>7)
  const int s1 = wave * 64 + lane;
  const int s2 = s1 + 256;
  const int r1 = s1 & 127, q1 = s1 >> 7;
  const int r2 = s2 & 127, q2 = s2 >> 7;

  // Each wave issues exactly 4 gload_lds per stage (vmcnt counting unit).
  auto stage = [&](int st) {
    short* base = &lds[(st % 3) * 8192];
    const int k0 = st * 32;
    gload_lds16(A + (size_t)(m0 + r1) * K + k0 + q1 * 8, base + wave * 512);
    gload_lds16(A + (size_t)(m0 + r2) * K + k0 + q2 * 8, base + 2048 + wave * 512);
    gload_lds16(W + (size_t)(n0 + r1) * K + k0 + q1 * 8, base + 4096 + wave * 512);
    gload_lds16(W + (size_t)(n0 + r2) * K + k0 + q2 * 8, base + 4096 + 2048 + wave * 512);
  };

  f32x4 acc[4][4];
#pragma unroll
  for (int i = 0; i < 4; ++i)
#pragma unroll
    for (int j = 0; j < 4; ++j) acc[i][j] = (f32x4){0.f, 0.f, 0.f, 0.f};

  const int NKT = K / 32;  // 24
  stage(0);
  stage(1);

  for (int kt = 0; kt < NKT; ++kt) {
    // Wait for stage(kt) only; stage(kt+1) stays in flight.
    if (kt < NKT - 1) {
      asm volatile("s_waitcnt vmcnt(4)" ::: "memory");
    } else {
      asm volatile("s_waitcnt vmcnt(0)" ::: "memory");
    }
    __builtin_amdgcn_s_barrier();
    __builtin_amdgcn_sched_barrier(0);
    if (kt + 2 < NKT) stage(kt + 2);   // writes buf (kt-1)%3: reads done pre-barrier
    __builtin_amdgcn_sched_barrier(0);

    const short* base = &lds[(kt % 3) * 8192];
    bf16x8 ah[4], bh[4];
#pragma unroll
    for (int mi = 0; mi < 4; ++mi) {
      ah[mi] = *(const bf16x8*)(base + lk * 1024 + (wr * 64 + mi * 16 + lr) * 8);
      bh[mi] = *(const bf16x8*)(base + 4096 + lk * 1024 + (wc * 64 + mi * 16 + lr) * 8);
    }
#pragma unroll
    for (int mi = 0; mi < 4; ++mi)
#pragma unroll
      for (int ni = 0; ni < 4; ++ni)
        acc[mi][ni] = __builtin_amdgcn_mfma_f32_16x16x32_bf16(ah[mi], bh[ni], acc[mi][ni], 0, 0, 0);
  }

  float* __restrict__ O =
      (MODE == 1) ? Oout : (z == 0 ? OK : (z == 1 ? OV : nullptr));
#pragma unroll
  for (int mi = 0; mi < 4; ++mi)
#pragma unroll
    for (int ni = 0; ni < 4; ++ni) {
      const int row = m0 + wr * 64 + mi * 16 + lk * 4;
      const int col = n0 + wc * 64 + ni * 16 + lr;
#pragma unroll
      for (int j = 0; j < 4; ++j) {
        float v = acc[mi][ni][j];
        if (MODE == 0 && z == 2) {
          float s = 1.f / (1.f + __expf(-v));
          OSR[(size_t)(row + j) * C_DIM + col] = f2bf(s);
        } else {
          O[(size_t)(row + j) * C_DIM + col] = v;
        }
      }
    }
}

// ---------------------------------------------------------------------------
// WKV chunk-parallel scan. Pass 1: per-(b,c,chunk) local transition triple.
// ---------------------------------------------------------------------------
#define P1_LOAD(kk_, vv_, base_)                                  \
  _Pragma("unroll") for (int j = 0; j < 8; ++j) {                 \
    int r_ = si[(base_) + j];                                     \
    kk_[j] = Kb[(size_t)r_ * C_DIM];                              \
    vv_[j] = Vb[(size_t)r_ * C_DIM];                              \
  }
#define P1_COMP(kk_, vv_)                                         \
  _Pragma("unroll") for (int j = 0; j < 8; ++j) {                 \
    float kt = kk_[j], vt = vv_[j];                               \
    float ww2 = w + pp; float p2 = fmaxf(ww2, kt);                \
    float e1b = __expf(ww2 - p2), e2b = __expf(kt - p2);          \
    aa = e1b * aa + e2b * vt; bb = e1b * bb + e2b; pp = p2;       \
  }

__global__ __launch_bounds__(256) void wkv_pass1(
    const float* __restrict__ Kin, const float* __restrict__ Vin,
    const int* __restrict__ sidx, const float* __restrict__ decay,
    float* __restrict__ aL, float* __restrict__ bL, float* __restrict__ pL)
{
  __shared__ int si[CHL];
  const int tid = threadIdx.x;
  const int ch = blockIdx.x, b = blockIdx.z;
  const int c = blockIdx.y * 256 + tid;
  if (tid < CHL) si[tid] = sidx[ch * CHL + tid];
  __syncthreads();
  const float w = decay[c] * (1.0f / (float)T_SEQ);
  const float* Kb = Kin + (size_t)b * T_SEQ * C_DIM + c;
  const float* Vb = Vin + (size_t)b * T_SEQ * C_DIM + c;
  float aa = 0.f, bb = 0.f, pp = -1e38f;
  float kA[8], vA[8], kB[8], vB[8];
  P1_LOAD(kA, vA, 0)
  for (int t0 = 0; t0 < CHL; t0 += 16) {
    P1_LOAD(kB, vB, t0 + 8)
    P1_COMP(kA, vA)
    if (t0 + 16 < CHL) { P1_LOAD(kA, vA, t0 + 16) }
    P1_COMP(kB, vB)
  }
  const int idx = (b * C_DIM + c) * NCH + ch;
  aL[idx] = aa; bL[idx] = bb; pL[idx] = pp;
}

// Serial scan over chunks per (b,c).
__global__ __launch_bounds__(256) void wkv_scan(
    const float* __restrict__ aL, const float* __restrict__ bL,
    const float* __restrict__ pL,
    float* __restrict__ aI, float* __restrict__ bI, float* __restrict__ pI,
    const float* __restrict__ decay)
{
  const int g = blockIdx.x * 256 + threadIdx.x;  // 0..6143 = b*C + c
  const int c = g % C_DIM;
  const float wL = decay[c] * ((float)CHL / (float)T_SEQ);
  float aa = 0.f, bb = 0.f, pp = -1e38f;
  const int base = g * NCH;
  for (int ch = 0; ch < NCH; ++ch) {
    aI[base + ch] = aa; bI[base + ch] = bb; pI[base + ch] = pp;
    float p1 = pp + wL;
    float p2 = pL[base + ch];
    float p  = fmaxf(p1, p2);
    float e1 = __expf(p1 - p), e2 = __expf(p2 - p);
    aa = e1 * aa + e2 * aL[base + ch];
    bb = e1 * bb + e2 * bL[base + ch];
    pp = p;
  }
}

// Pass 2: replay chunk with incoming state; y scattered to natural order.
#define P2_LOAD(rr_, kk_, vv_, base_)                             \
  _Pragma("unroll") for (int j = 0; j < 8; ++j) {                 \
    int r_ = si[(base_) + j];                                     \
    rr_[j] = r_;                                                  \
    kk_[j] = Kb[(size_t)r_ * C_DIM];                              \
    vv_[j] = Vb[(size_t)r_ * C_DIM];                              \
  }
#define P2_COMP(rr_, kk_, vv_)                                    \
  _Pragma("unroll") for (int j = 0; j < 8; ++j) {                 \
    float kt = kk_[j], vt = vv_[j];                               \
    float ww = u + kt; float p = fmaxf(pp, ww);                   \
    float e1 = __expf(pp - p), e2 = __expf(ww - p);               \
    Yb[(size_t)rr_[j] * C_DIM] = (e1 * aa + e2 * vt) / (e1 * bb + e2); \
    float ww2 = w + pp; float p2 = fmaxf(ww2, kt);                \
    float e1b = __expf(ww2 - p2), e2b = __expf(kt - p2);          \
    aa = e1b * aa + e2b * vt; bb = e1b * bb + e2b; pp = p2;       \
  }

__global__ __launch_bounds__(256) void wkv_pass2(
    const float* __restrict__ Kin, const float* __restrict__ Vin,
    const int* __restrict__ sidx,
    const float* __restrict__ decay, const float* __restrict__ first,
    const float* __restrict__ aI, const float* __restrict__ bI,
    const float* __restrict__ pI, float* __restrict__ Y)
{
  __shared__ int si[CHL];
  const int tid = threadIdx.x;
  const int ch = blockIdx.x, b = blockIdx.z;
  const int c = blockIdx.y * 256 + tid;
  if (tid < CHL) si[tid] = sidx[ch * CHL + tid];
  __syncthreads();
  const float w = decay[c] * (1.0f / (float)T_SEQ);
  const float u = first[c] * (1.0f / (float)T_SEQ);
  const float* Kb = Kin + (size_t)b * T_SEQ * C_DIM + c;
  const float* Vb = Vin + (size_t)b * T_SEQ * C_DIM + c;
  float* Yb = Y + (size_t)b * T_SEQ * C_DIM + c;
  const int idx = (b * C_DIM + c) * NCH + ch;
  float aa = aI[idx], bb = bI[idx], pp = pI[idx];
  int rA[8], rB[8]; float kA[8], vA[8], kB[8], vB[8];
  P2_LOAD(rA, kA, vA, 0)
  for (int t0 = 0; t0 < CHL; t0 += 16) {
    P2_LOAD(rB, kB, vB, t0 + 8)
    P2_COMP(rA, kA, vA)
    if (t0 + 16 < CHL) { P2_LOAD(rA, kA, vA, t0 + 16) }
    P2_COMP(rB, kB, vB)
  }
}

// ---------------------------------------------------------------------------
// Row LayerNorm over C + sigmoid gate; writes bf16 operand for output GEMM.
// ---------------------------------------------------------------------------
__global__ __launch_bounds__(256) void ln_gate(
    const float* __restrict__ Y, const unsigned short* __restrict__ SR,
    const float* __restrict__ gam, const float* __restrict__ bet,
    unsigned short* __restrict__ G)
{
  const size_t row = blockIdx.x;
  const float* x = Y + row * C_DIM;
  const unsigned short* sr = SR + row * C_DIM;
  unsigned short* go = G + row * C_DIM;
  const int tid = threadIdx.x;

  float vals[3];
  float s = 0.f, s2 = 0.f;
#pragma unroll
  for (int j = 0; j < 3; ++j) {
    float v = x[tid + j * 256];
    vals[j] = v;
    s += v; s2 += v * v;
  }
#pragma unroll
  for (int off = 32; off >= 1; off >>= 1) {
    s  += __shfl_xor(s, off, 64);
    s2 += __shfl_xor(s2, off, 64);
  }
  __shared__ float red[8];
  const int wid = tid >> 6;
  if ((tid & 63) == 0) { red[wid] = s; red[wid + 4] = s2; }
  __syncthreads();
  s  = red[0] + red[1] + red[2] + red[3];
  s2 = red[4] + red[5] + red[6] + red[7];

  const float mu   = s * (1.f / (float)C_DIM);
  const float var  = s2 * (1.f / (float)C_DIM) - mu * mu;
  const float rsig = rsqrtf(var + 1e-5f);

#pragma unroll
  for (int j = 0; j < 3; ++j) {
    const int cc = tid + j * 256;
    float yv = (vals[j] - mu) * rsig * gam[cc] + bet[cc];
    go[cc] = f2bf(yv * bf2f(sr[cc]));
  }
}

// ---------------------------------------------------------------------------
extern "C" void kernel_launch(void* const* d_in, const int* in_sizes, int n_in,
                              void* d_out, int out_size, void* d_ws, size_t ws_size,
                              hipStream_t stream) {
  const float* x     = (const float*)d_in[0];
  const int*   sidx  = (const int*)  d_in[1];
  const float* decay = (const float*)d_in[2];
  const float* first = (const float*)d_in[3];
  const float* Wk    = (const float*)d_in[4];
  const float* Wv    = (const float*)d_in[5];
  const float* Wr    = (const float*)d_in[6];
  const float* Wo    = (const float*)d_in[7];
  const float* ln_g  = (const float*)d_in[8];
  const float* ln_b  = (const float*)d_in[9];
  float* out = (float*)d_out;

  const size_t NE = (size_t)M_ROWS * C_DIM;  // 25165824
  // Workspace layout (~362 MB):
  short* Whs  = (short*)d_ws;                    // 4*CC bf16
  float* Ybuf = (float*)(Whs + 4 * (size_t)CC);  // NE f32 (x_hi aliases front)
  short* x_hi = (short*)Ybuf;                    // NE bf16 (dead before Y written)
  float* Kbuf = Ybuf + NE;                       // NE f32
  unsigned short* Gbuf = (unsigned short*)Kbuf;  // alias: after K dead
  float* Vbuf = Kbuf + NE;                       // NE f32
  unsigned short* SRb = (unsigned short*)(Vbuf + NE); // NE bf16
  float* aL = (float*)(SRb + NE);                // 6 x 196608 f32
  float* bL = aL + 196608;
  float* pL = bL + 196608;
  float* aI = pL + 196608;
  float* bI = aI + 196608;
  float* pI = bI + 196608;

  // 1) bf16 conversions (x + all 4 weights in one dispatch)
  convert_x<<<24576, 256, 0, stream>>>((const float4*)x, (ushort4*)x_hi);
  convert_w4<<<dim3(576, 4), 256, 0, stream>>>(
      (const float4*)Wk, (const float4*)Wv, (const float4*)Wr, (const float4*)Wo,
      (ushort4*)Whs);

  // 2) k, v (f32 out), sr = sigmoid(r) (bf16 out) in one dispatch
  gemm_pipe<0><<<dim3(6, 256, 3), 256, 0, stream>>>(
      x_hi, Whs, Kbuf, Vbuf, SRb, nullptr);

  // 3) WKV: chunk transitions -> serial chunk scan -> replay with y output
  wkv_pass1<<<dim3(NCH, 3, B_DIM), 256, 0, stream>>>(Kbuf, Vbuf, sidx, decay, aL, bL, pL);
  wkv_scan<<<24, 256, 0, stream>>>(aL, bL, pL, aI, bI, pI, decay);
  wkv_pass2<<<dim3(NCH, 3, B_DIM), 256, 0, stream>>>(Kbuf, Vbuf, sidx, decay, first,
                                                     aI, bI, pI, Ybuf);
  // 4) LayerNorm + gate -> bf16 GEMM operand (G aliases K; K dead now)
  ln_gate<<<M_ROWS, 256, 0, stream>>>(Ybuf, SRb, ln_g, ln_b, Gbuf);
  // 5) out = G @ Wo^T
  gemm_pipe<1><<<dim3(6, 256, 1), 256, 0, stream>>>(
      (const short*)Gbuf, Whs + 3 * (size_t)CC, nullptr, nullptr, nullptr, out);
}

// Round 5
// 450.410 us; speedup vs baseline: 6.1662x; 1.0978x over previous
//
#include <hip/hip_runtime.h>
#include <cstddef>
#include <cstdint>

#define B_DIM 8
#define T_SEQ 4096
#define C_DIM 768
#define M_ROWS (B_DIM * T_SEQ)   // 32768
#define CC (C_DIM * C_DIM)       // 589824
#define NCH 32
#define CHL (T_SEQ / NCH)        // 128

using bf16x8 = __attribute__((ext_vector_type(8))) short;
using f32x4  = __attribute__((ext_vector_type(4))) float;

static __device__ __forceinline__ unsigned short f2bf(float f) {
  unsigned int u = __float_as_uint(f);
  return (unsigned short)((u + 0x7fffu + ((u >> 16) & 1u)) >> 16);
}
static __device__ __forceinline__ float bf2f(unsigned short s) {
  return __uint_as_float(((unsigned int)s) << 16);
}

static __device__ __forceinline__ void gload_lds16(const void* g, void* l) {
  __builtin_amdgcn_global_load_lds(
      (const __attribute__((address_space(1))) unsigned int*)g,
      (__attribute__((address_space(3))) unsigned int*)l, 16, 0, 0);
}

// ---------------------------------------------------------------------------
// f32 -> bf16 converts.
// ---------------------------------------------------------------------------
__global__ __launch_bounds__(256) void convert_x(
    const float4* __restrict__ x, ushort4* __restrict__ xh)
{
  int i = blockIdx.x * 256 + threadIdx.x;
  float4 v = x[i];
  ushort4 h;
  h.x = f2bf(v.x); h.y = f2bf(v.y); h.z = f2bf(v.z); h.w = f2bf(v.w);
  xh[i] = h;
}

__global__ __launch_bounds__(256) void convert_w4(
    const float4* __restrict__ w0, const float4* __restrict__ w1,
    const float4* __restrict__ w2, const float4* __restrict__ w3,
    ushort4* __restrict__ dst)
{
  const int z = blockIdx.y;
  const float4* __restrict__ src = (z == 0) ? w0 : (z == 1) ? w1 : (z == 2) ? w2 : w3;
  int i = blockIdx.x * 256 + threadIdx.x;
  float4 v = src[i];
  ushort4 h;
  h.x = f2bf(v.x); h.y = f2bf(v.y); h.z = f2bf(v.z); h.w = f2bf(v.w);
  dst[(size_t)z * (CC / 4) + i] = h;
}

// ---------------------------------------------------------------------------
// 8-phase 256x256 MFMA GEMM (NT): O[m,n] = sum_k A[m,k]*W[n,k], K = 768.
// BK=64, 8 waves (2M x 4N), per-wave 128x64 output, 16x16x32 bf16 MFMA.
// LDS 128 KB dynamic: 2 bufs x (A 32KB | B 32KB); layout per buf:
//   region + kh*16384 + q*4096 + row*16   (kh: k-half of 32, q: 8-bf16 chunk)
// -> ds_read_b128 conflict-free (consecutive lanes = consecutive 16B).
// Schedule per iteration (2 K-tiles, 8 phases): each phase = {ds_read 4a[+4b],
// stage one 16KB half, barrier, lgkmcnt(0), setprio(1), 16 MFMA, setprio(0),
// [vmcnt(4) at P3/P7], barrier}. Stage targets verified dead >=1 phase prior;
// vmcnt(4) covers every read with 2 halves left in flight. Never drains in
// steady state (T3+T4+T5).
// MODE 0: fused kvr, N=2304 over [Wk|Wv|Wr]; n<768 -> K f32, <1536 -> V f32,
//         else sigmoid -> bf16 SR.   MODE 1: out-GEMM, N=768, f32.
// ---------------------------------------------------------------------------
#define STG_A(DBYTE, TAU, KH) do {                                        \
    const int ko_ = (TAU) * 64 + (KH) * 32;                               \
    short* d_ = lds + (((DBYTE) + (KH) * 16384) >> 1);                    \
    gload_lds16(pA0 + ko_, d_ + ub0 * 8);                                 \
    gload_lds16(pA1 + ko_, d_ + ub1 * 8);                                 \
  } while (0)
#define STG_B(DBYTE, TAU, KH) do {                                        \
    const int ko_ = (TAU) * 64 + (KH) * 32;                               \
    short* d_ = lds + (((DBYTE) + 32768 + (KH) * 16384) >> 1);            \
    gload_lds16(pW0 + ko_, d_ + ub0 * 8);                                 \
    gload_lds16(pW1 + ko_, d_ + ub1 * 8);                                 \
  } while (0)

#define PHASE(DB, KH, MQ, READB, STAGE, CKPT)                             \
  {                                                                        \
    _Pragma("unroll")                                                      \
    for (int mi = 0; mi < 4; ++mi)                                         \
      a[mi] = *(const bf16x8*)(lds +                                       \
          (((DB) + (KH) * 16384 + aoff + ((MQ) * 4 + mi) * 256) >> 1));    \
    if (READB) {                                                           \
      _Pragma("unroll")                                                    \
      for (int ni = 0; ni < 4; ++ni)                                       \
        b[ni] = *(const bf16x8*)(lds +                                     \
            (((DB) + (KH) * 16384 + boff + ni * 256) >> 1));               \
    }                                                                      \
    STAGE;                                                                 \
    __builtin_amdgcn_s_barrier();                                          \
    asm volatile("s_waitcnt lgkmcnt(0)" ::: "memory");                     \
    __builtin_amdgcn_sched_barrier(0);                                     \
    __builtin_amdgcn_s_setprio(1);                                         \
    _Pragma("unroll")                                                      \
    for (int mi = 0; mi < 4; ++mi)                                         \
      _Pragma("unroll")                                                    \
      for (int ni = 0; ni < 4; ++ni)                                       \
        acc[(MQ) * 4 + mi][ni] = __builtin_amdgcn_mfma_f32_16x16x32_bf16(  \
            a[mi], b[ni], acc[(MQ) * 4 + mi][ni], 0, 0, 0);                \
    __builtin_amdgcn_s_setprio(0);                                         \
    CKPT;                                                                  \
    __builtin_amdgcn_s_barrier();                                          \
  }

template<int MODE>
__global__ __launch_bounds__(512, 2) void gemm8p(
    const short* __restrict__ A, const short* __restrict__ Wb,
    float* __restrict__ OK, float* __restrict__ OV,
    unsigned short* __restrict__ OSR, float* __restrict__ Oout)
{
  extern __shared__ short lds[];   // 128 KB
  const int K = C_DIM;
  constexpr int NWN = (MODE == 0) ? 9 : 3;     // n-tiles
  constexpr int CPX = (MODE == 0) ? 144 : 48;  // blocks per XCD (bijective)

  int f  = blockIdx.x + blockIdx.y * NWN;
  int wg = (f & 7) * CPX + (f >> 3);
  const int n0 = (wg % NWN) * 256;
  const int m0 = (wg / NWN) * 256;

  const int tid  = threadIdx.x;
  const int lane = tid & 63, wave = tid >> 6;
  const int wr = wave >> 2, wc = wave & 3;   // 2M x 4N wave grid
  const int lr = lane & 15, lk = lane >> 4;

  // fragment LDS byte offsets (within one buffer region)
  const int aoff = lk * 4096 + wr * 2048 + lr * 16;
  const int boff = 32768 + lk * 4096 + wc * 1024 + lr * 16;

  // staging: slot u = wave*128 + ld*64 + lane; row = u&255, q = u>>8
  const int ub0 = wave * 128;
  const int ub1 = wave * 128 + 64;
  const int r0 = (ub0 & 255) + lane, q0 = ub0 >> 8;
  const int r1 = (ub1 & 255) + lane, q1 = ub1 >> 8;
  const short* pA0 = A  + (size_t)(m0 + r0) * K + q0 * 8;
  const short* pA1 = A  + (size_t)(m0 + r1) * K + q1 * 8;
  const short* pW0 = Wb + (size_t)(n0 + r0) * K + q0 * 8;
  const short* pW1 = Wb + (size_t)(n0 + r1) * K + q1 * 8;

  f32x4 acc[8][4];
#pragma unroll
  for (int i = 0; i < 8; ++i)
#pragma unroll
    for (int j = 0; j < 4; ++j) acc[i][j] = (f32x4){0.f, 0.f, 0.f, 0.f};

  // Prologue: stage tiles 0 (buf0) and 1 (buf1) fully; wait tile 0.
  STG_A(0, 0, 0); STG_B(0, 0, 0); STG_A(0, 0, 1); STG_B(0, 0, 1);
  STG_A(65536, 1, 0); STG_B(65536, 1, 0); STG_A(65536, 1, 1); STG_B(65536, 1, 1);
  asm volatile("s_waitcnt vmcnt(8)" ::: "memory");
  __builtin_amdgcn_s_barrier();

  bf16x8 a[4], b[4];
  // 12 K-tiles, 2 per iteration. Stage queue (lag 2 phases):
  //  P0: t(2it+1).A-kh1  P1: t(2it+1).B-kh1   [it>=1]
  //  P2: t(2it+2).A-kh0  P3: t(2it+2).B-kh0   [it<5]
  //  P4: t(2it+2).A-kh1  P5: t(2it+2).B-kh1   [it<5]
  //  P6: t(2it+3).A-kh0  P7: t(2it+3).B-kh0   [it<5]
  for (int it = 0; it < 6; ++it) {
    PHASE(0, 0, 0, 1, if (it >= 1) STG_A(65536, 2 * it + 1, 1), )
    PHASE(0, 0, 1, 0, if (it >= 1) STG_B(65536, 2 * it + 1, 1), )
    PHASE(0, 1, 0, 1, if (it < 5) STG_A(0, 2 * it + 2, 0), )
    PHASE(0, 1, 1, 0, if (it < 5) STG_B(0, 2 * it + 2, 0),
          if (it < 5) { asm volatile("s_waitcnt vmcnt(4)" ::: "memory"); }
          else       { asm volatile("s_waitcnt vmcnt(0)" ::: "memory"); })
    PHASE(65536, 0, 0, 1, if (it < 5) STG_A(0, 2 * it + 2, 1), )
    PHASE(65536, 0, 1, 0, if (it < 5) STG_B(0, 2 * it + 2, 1), )
    PHASE(65536, 1, 0, 1, if (it < 5) STG_A(65536, 2 * it + 3, 0), )
    PHASE(65536, 1, 1, 0, if (it < 5) STG_B(65536, 2 * it + 3, 0),
          if (it < 5) { asm volatile("s_waitcnt vmcnt(4)" ::: "memory"); })
  }

  // Epilogue
  if (MODE == 0) {
    const int which = n0 / 768;               // 0:K 1:V 2:SR (BN=256 | 768)
    const int nc = (n0 % 768) + wc * 64;
#pragma unroll
    for (int mi = 0; mi < 8; ++mi)
#pragma unroll
      for (int ni = 0; ni < 4; ++ni) {
        const int row = m0 + wr * 128 + mi * 16 + lk * 4;
        const int col = nc + ni * 16 + lr;
#pragma unroll
        for (int j = 0; j < 4; ++j) {
          float v = acc[mi][ni][j];
          if (which == 2) {
            float s = 1.f / (1.f + __expf(-v));
            OSR[(size_t)(row + j) * C_DIM + col] = f2bf(s);
          } else {
            float* O = which ? OV : OK;
            O[(size_t)(row + j) * C_DIM + col] = v;
          }
        }
      }
  } else {
#pragma unroll
    for (int mi = 0; mi < 8; ++mi)
#pragma unroll
      for (int ni = 0; ni < 4; ++ni) {
        const int row = m0 + wr * 128 + mi * 16 + lk * 4;
        const int col = n0 + wc * 64 + ni * 16 + lr;
#pragma unroll
        for (int j = 0; j < 4; ++j)
          Oout[(size_t)(row + j) * C_DIM + col] = acc[mi][ni][j];
      }
  }
}

// ---------------------------------------------------------------------------
// WKV chunk-parallel scan. Pass 1: per-(b,c,chunk) local transition triple.
// ---------------------------------------------------------------------------
#define P1_LOAD(kk_, vv_, base_)                                  \
  _Pragma("unroll") for (int j = 0; j < 8; ++j) {                 \
    int r_ = si[(base_) + j];                                     \
    kk_[j] = Kb[(size_t)r_ * C_DIM];                              \
    vv_[j] = Vb[(size_t)r_ * C_DIM];                              \
  }
#define P1_COMP(kk_, vv_)                                         \
  _Pragma("unroll") for (int j = 0; j < 8; ++j) {                 \
    float kt = kk_[j], vt = vv_[j];                               \
    float ww2 = w + pp; float p2 = fmaxf(ww2, kt);                \
    float e1b = __expf(ww2 - p2), e2b = __expf(kt - p2);          \
    aa = e1b * aa + e2b * vt; bb = e1b * bb + e2b; pp = p2;       \
  }

__global__ __launch_bounds__(256) void wkv_pass1(
    const float* __restrict__ Kin, const float* __restrict__ Vin,
    const int* __restrict__ sidx, const float* __restrict__ decay,
    float* __restrict__ aL, float* __restrict__ bL, float* __restrict__ pL)
{
  __shared__ int si[CHL];
  const int tid = threadIdx.x;
  const int ch = blockIdx.x, b = blockIdx.z;
  const int c = blockIdx.y * 256 + tid;
  if (tid < CHL) si[tid] = sidx[ch * CHL + tid];
  __syncthreads();
  const float w = decay[c] * (1.0f / (float)T_SEQ);
  const float* Kb = Kin + (size_t)b * T_SEQ * C_DIM + c;
  const float* Vb = Vin + (size_t)b * T_SEQ * C_DIM + c;
  float aa = 0.f, bb = 0.f, pp = -1e38f;
  float kA[8], vA[8], kB[8], vB[8];
  P1_LOAD(kA, vA, 0)
  for (int t0 = 0; t0 < CHL; t0 += 16) {
    P1_LOAD(kB, vB, t0 + 8)
    P1_COMP(kA, vA)
    if (t0 + 16 < CHL) { P1_LOAD(kA, vA, t0 + 16) }
    P1_COMP(kB, vB)
  }
  const int idx = (b * C_DIM + c) * NCH + ch;
  aL[idx] = aa; bL[idx] = bb; pL[idx] = pp;
}

// Serial scan over chunks per (b,c).
__global__ __launch_bounds__(256) void wkv_scan(
    const float* __restrict__ aL, const float* __restrict__ bL,
    const float* __restrict__ pL,
    float* __restrict__ aI, float* __restrict__ bI, float* __restrict__ pI,
    const float* __restrict__ decay)
{
  const int g = blockIdx.x * 256 + threadIdx.x;  // 0..6143 = b*C + c
  const int c = g % C_DIM;
  const float wL = decay[c] * ((float)CHL / (float)T_SEQ);
  float aa = 0.f, bb = 0.f, pp = -1e38f;
  const int base = g * NCH;
  for (int ch = 0; ch < NCH; ++ch) {
    aI[base + ch] = aa; bI[base + ch] = bb; pI[base + ch] = pp;
    float p1 = pp + wL;
    float p2 = pL[base + ch];
    float p  = fmaxf(p1, p2);
    float e1 = __expf(p1 - p), e2 = __expf(p2 - p);
    aa = e1 * aa + e2 * aL[base + ch];
    bb = e1 * bb + e2 * bL[base + ch];
    pp = p;
  }
}

// Pass 2: replay chunk with incoming state; y scattered to natural order.
#define P2_LOAD(rr_, kk_, vv_, base_)                             \
  _Pragma("unroll") for (int j = 0; j < 8; ++j) {                 \
    int r_ = si[(base_) + j];                                     \
    rr_[j] = r_;                                                  \
    kk_[j] = Kb[(size_t)r_ * C_DIM];                              \
    vv_[j] = Vb[(size_t)r_ * C_DIM];                              \
  }
#define P2_COMP(rr_, kk_, vv_)                                    \
  _Pragma("unroll") for (int j = 0; j < 8; ++j) {                 \
    float kt = kk_[j], vt = vv_[j];                               \
    float ww = u + kt; float p = fmaxf(pp, ww);                   \
    float e1 = __expf(pp - p), e2 = __expf(ww - p);               \
    Yb[(size_t)rr_[j] * C_DIM] = (e1 * aa + e2 * vt) / (e1 * bb + e2); \
    float ww2 = w + pp; float p2 = fmaxf(ww2, kt);                \
    float e1b = __expf(ww2 - p2), e2b = __expf(kt - p2);          \
    aa = e1b * aa + e2b * vt; bb = e1b * bb + e2b; pp = p2;       \
  }

__global__ __launch_bounds__(256) void wkv_pass2(
    const float* __restrict__ Kin, const float* __restrict__ Vin,
    const int* __restrict__ sidx,
    const float* __restrict__ decay, const float* __restrict__ first,
    const float* __restrict__ aI, const float* __restrict__ bI,
    const float* __restrict__ pI, float* __restrict__ Y)
{
  __shared__ int si[CHL];
  const int tid = threadIdx.x;
  const int ch = blockIdx.x, b = blockIdx.z;
  const int c = blockIdx.y * 256 + tid;
  if (tid < CHL) si[tid] = sidx[ch * CHL + tid];
  __syncthreads();
  const float w = decay[c] * (1.0f / (float)T_SEQ);
  const float u = first[c] * (1.0f / (float)T_SEQ);
  const float* Kb = Kin + (size_t)b * T_SEQ * C_DIM + c;
  const float* Vb = Vin + (size_t)b * T_SEQ * C_DIM + c;
  float* Yb = Y + (size_t)b * T_SEQ * C_DIM + c;
  const int idx = (b * C_DIM + c) * NCH + ch;
  float aa = aI[idx], bb = bI[idx], pp = pI[idx];
  int rA[8], rB[8]; float kA[8], vA[8], kB[8], vB[8];
  P2_LOAD(rA, kA, vA, 0)
  for (int t0 = 0; t0 < CHL; t0 += 16) {
    P2_LOAD(rB, kB, vB, t0 + 8)
    P2_COMP(rA, kA, vA)
    if (t0 + 16 < CHL) { P2_LOAD(rA, kA, vA, t0 + 16) }
    P2_COMP(rB, kB, vB)
  }
}

// ---------------------------------------------------------------------------
// Row LayerNorm over C + sigmoid gate; writes bf16 operand for output GEMM.
// ---------------------------------------------------------------------------
__global__ __launch_bounds__(256) void ln_gate(
    const float* __restrict__ Y, const unsigned short* __restrict__ SR,
    const float* __restrict__ gam, const float* __restrict__ bet,
    unsigned short* __restrict__ G)
{
  const size_t row = blockIdx.x;
  const float* x = Y + row * C_DIM;
  const unsigned short* sr = SR + row * C_DIM;
  unsigned short* go = G + row * C_DIM;
  const int tid = threadIdx.x;

  float vals[3];
  float s = 0.f, s2 = 0.f;
#pragma unroll
  for (int j = 0; j < 3; ++j) {
    float v = x[tid + j * 256];
    vals[j] = v;
    s += v; s2 += v * v;
  }
#pragma unroll
  for (int off = 32; off >= 1; off >>= 1) {
    s  += __shfl_xor(s, off, 64);
    s2 += __shfl_xor(s2, off, 64);
  }
  __shared__ float red[8];
  const int wid = tid >> 6;
  if ((tid & 63) == 0) { red[wid] = s; red[wid + 4] = s2; }
  __syncthreads();
  s  = red[0] + red[1] + red[2] + red[3];
  s2 = red[4] + red[5] + red[6] + red[7];

  const float mu   = s * (1.f / (float)C_DIM);
  const float var  = s2 * (1.f / (float)C_DIM) - mu * mu;
  const float rsig = rsqrtf(var + 1e-5f);

#pragma unroll
  for (int j = 0; j < 3; ++j) {
    const int cc = tid + j * 256;
    float yv = (vals[j] - mu) * rsig * gam[cc] + bet[cc];
    go[cc] = f2bf(yv * bf2f(sr[cc]));
  }
}

// ---------------------------------------------------------------------------
extern "C" void kernel_launch(void* const* d_in, const int* in_sizes, int n_in,
                              void* d_out, int out_size, void* d_ws, size_t ws_size,
                              hipStream_t stream) {
  const float* x     = (const float*)d_in[0];
  const int*   sidx  = (const int*)  d_in[1];
  const float* decay = (const float*)d_in[2];
  const float* first = (const float*)d_in[3];
  const float* Wk    = (const float*)d_in[4];
  const float* Wv    = (const float*)d_in[5];
  const float* Wr    = (const float*)d_in[6];
  const float* Wo    = (const float*)d_in[7];
  const float* ln_g  = (const float*)d_in[8];
  const float* ln_b  = (const float*)d_in[9];
  float* out = (float*)d_out;

  const size_t NE = (size_t)M_ROWS * C_DIM;  // 25165824
  // Workspace layout (~362 MB):
  short* Whs  = (short*)d_ws;                    // 4*CC bf16 [Wk|Wv|Wr|Wo]
  float* Ybuf = (float*)(Whs + 4 * (size_t)CC);  // NE f32 (x_hi aliases front)
  short* x_hi = (short*)Ybuf;                    // NE bf16 (dead before Y written)
  float* Kbuf = Ybuf + NE;                       // NE f32
  unsigned short* Gbuf = (unsigned short*)Kbuf;  // alias: after K dead
  float* Vbuf = Kbuf + NE;                       // NE f32
  unsigned short* SRb = (unsigned short*)(Vbuf + NE); // NE bf16
  float* aL = (float*)(SRb + NE);                // 6 x 196608 f32
  float* bL = aL + 196608;
  float* pL = bL + 196608;
  float* aI = pL + 196608;
  float* bI = aI + 196608;
  float* pI = bI + 196608;

  // Allow 128 KB dynamic LDS for the 8-phase GEMMs (idempotent, capture-safe).
  (void)hipFuncSetAttribute(reinterpret_cast<const void*>(&gemm8p<0>),
                            hipFuncAttributeMaxDynamicSharedMemorySize, 131072);
  (void)hipFuncSetAttribute(reinterpret_cast<const void*>(&gemm8p<1>),
                            hipFuncAttributeMaxDynamicSharedMemorySize, 131072);

  // 1) bf16 conversions
  convert_x<<<24576, 256, 0, stream>>>((const float4*)x, (ushort4*)x_hi);
  convert_w4<<<dim3(576, 4), 256, 0, stream>>>(
      (const float4*)Wk, (const float4*)Wv, (const float4*)Wr, (const float4*)Wo,
      (ushort4*)Whs);

  // 2) fused k|v|sr GEMM: M=32768, N=2304, K=768 (1152 blocks of 256^2)
  gemm8p<0><<<dim3(9, 128), 512, 131072, stream>>>(
      x_hi, Whs, Kbuf, Vbuf, SRb, nullptr);

  // 3) WKV: chunk transitions -> serial chunk scan -> replay with y output
  wkv_pass1<<<dim3(NCH, 3, B_DIM), 256, 0, stream>>>(Kbuf, Vbuf, sidx, decay, aL, bL, pL);
  wkv_scan<<<24, 256, 0, stream>>>(aL, bL, pL, aI, bI, pI, decay);
  wkv_pass2<<<dim3(NCH, 3, B_DIM), 256, 0, stream>>>(Kbuf, Vbuf, sidx, decay, first,
                                                     aI, bI, pI, Ybuf);
  // 4) LayerNorm + gate -> bf16 GEMM operand (G aliases K; K dead now)
  ln_gate<<<M_ROWS, 256, 0, stream>>>(Ybuf, SRb, ln_g, ln_b, Gbuf);
  // 5) out = G @ Wo^T (384 blocks of 256^2)
  gemm8p<1><<<dim3(3, 128), 512, 131072, stream>>>(
      (const short*)Gbuf, Whs + 3 * (size_t)CC, nullptr, nullptr, nullptr, out);
}